// Round 7
// baseline (106.309 us; speedup 1.0000x reference)
//
#include <hip/hip_runtime.h>

#define B    64
#define T    2000
#define DQ   1024
#define DM   512
#define D    128
#define F    32
#define KK   31
#define WIN  7
#define NCH  32
#define CH   63            // ceil(T/NCH)
#define NCS  (B * NCH)     // 2048 colsum blocks (dispatched first)

#define SENT 0x5A17C0DE900DF00DULL

// ws layout:
//   part : [B][NCH][DM] floats @ 0            (4 MB)
//   flag : [B][NCH] u64        @ after part   (16 KB)
// out layout (floats):
//   attention  [B][D]  @ 0
//   alignments [B][T]  @ 8192
//   next_state [B][T]  @ 8192 + B*T
//   max_att    [B]     @ 8192 + 2*B*T  (as float)
#define OUT_ALIGN 8192
#define OUT_NEXT  (8192 + B*T)
#define OUT_ARG   (8192 + 2*B*T)

// Single kernel, two block roles:
//  blocks [0,NCS)        : degenerate colsum partial (b=blk>>5, c=blk&31)
//                          -> part, threadfence, release-store sentinel flag
//  blocks [NCS,NCS+B)    : per-batch energy/softmax/[B,T] outputs/argmax;
//                          non-deg: window-ctx GEMV -> attention;
//                          deg: spin on 32 flags (acquire), reduce fixed order,
//                               GEMV, write attention, reset flags to 0.
// lowmem (ws too small): grid = B, energy blocks only, in-block slow colsum.
__global__ void __launch_bounds__(512)
KF(const float* __restrict__ q, const float* __restrict__ mem,
   const float* __restrict__ pa, const int* __restrict__ pm, const int* __restrict__ ml,
   const float* __restrict__ Wq, const float* __restrict__ Wm,
   const float* __restrict__ ck, const float* __restrict__ cb,
   const float* __restrict__ Wloc, const float* __restrict__ sv,
   const float* __restrict__ sb, float* __restrict__ part,
   unsigned long long* __restrict__ flag, float* __restrict__ out,
   int cs_blocks, int lowmem) {
    __shared__ float smem_a[DQ];          // qs during pq; later ctxs[512]+gpart[512]
    __shared__ float pqpart[4][D];
    __shared__ float pqs[D];
    __shared__ float mrow[WIN][DM];
    __shared__ float fsh[WIN][F];
    __shared__ float2 pacc2[WIN][8][64];
    __shared__ float esh[WIN];
    __shared__ float ash[WIN];
    __shared__ int   sbest;

    float* qs = smem_a;
    float* ctxs = smem_a;
    float* gpart = smem_a + DM;

    int blk = blockIdx.x;
    int tid = threadIdx.x;

    if (blk < cs_blocks) {
        // ---------------- degenerate colsum partial ----------------
        int b = blk >> 5, c = blk & 31;
        if (pm[b] < ml[b]) return;              // non-degenerate: nothing to do
        int t0 = c * CH, t1 = t0 + CH;
        if (t1 > T) t1 = T;
        const float* mp = mem + ((size_t)b * T + t0) * DM + tid;
        float a0 = 0.f, a1 = 0.f, a2 = 0.f, a3 = 0.f;
        int t = t0;
        for (; t + 4 <= t1; t += 4) {
            a0 += mp[0];
            a1 += mp[DM];
            a2 += mp[2 * DM];
            a3 += mp[3 * DM];
            mp += 4 * (size_t)DM;
        }
        for (; t < t1; ++t) { a0 += *mp; mp += DM; }
        part[((size_t)b * NCH + c) * DM + tid] = ((a0 + a1) + (a2 + a3)) * (1.f / (float)T);
        __threadfence();                        // push to device coherence point
        __syncthreads();                        // all lanes' stores before flag
        if (tid == 0)
            __hip_atomic_store(&flag[b * NCH + c], SENT,
                               __ATOMIC_RELEASE, __HIP_MEMORY_SCOPE_AGENT);
        return;
    }

    // ---------------- per-batch energy / softmax / outputs ----------------
    int b = blk - cs_blocks;
    int lane = tid & 63;
    int wave = tid >> 6;
    int p = pm[b], L = ml[b];
    int wstart = p, wlen = 0;
    if (p < L) { int we = p + WIN; if (we > L) we = L; wlen = we - p; }

    if (wlen > 0) {
        qs[tid] = q[(size_t)b * DQ + tid];
        qs[tid + 512] = q[(size_t)b * DQ + tid + 512];
        for (int e = tid; e < WIN * DM; e += 512) {
            int i = e >> 9, m = e & 511;
            mrow[i][m] = (i < wlen) ? mem[((size_t)b * T + wstart + i) * DM + m] : 0.f;
        }
        if (tid < WIN * F) {
            int i = tid >> 5, f = tid & 31;
            if (i < wlen) {
                int t = wstart + i;
                float acc = cb[f];
                for (int k = 0; k < KK; ++k) {
                    int tt = t + k - 15;
                    float x = (tt >= 0 && tt < T) ? pa[(size_t)b * T + tt] : 0.f;
                    acc += x * ck[k * F + f];
                }
                fsh[i][f] = acc;
            } else if (i < WIN) {
                fsh[i][f] = 0.f;
            }
        }
        __syncthreads();

        // pq partials: (j=tid>>7, d=tid&127), each sums 256 of 1024 k
        {
            int d = tid & 127, j = tid >> 7;
            int k0 = j * 256;
            float acc = 0.f;
            for (int k = 0; k < 256; ++k)
                acc += qs[k0 + k] * Wq[(size_t)(k0 + k) * D + d];
            pqpart[j][d] = acc;
        }
        __syncthreads();
        if (tid < D)
            pqs[tid] = pqpart[0][tid] + pqpart[1][tid] + pqpart[2][tid] + pqpart[3][tid] + sb[tid];

        // m-split energies: wave w owns rows [w*64,(w+1)*64), all WIN positions
        {
            const float2* Wm2 = (const float2*)Wm;
            float2 acc[WIN];
            #pragma unroll
            for (int i = 0; i < WIN; ++i) { acc[i].x = 0.f; acc[i].y = 0.f; }
            int m0 = wave * 64;
            for (int mm = 0; mm < 64; ++mm) {
                int m = m0 + mm;
                float2 wrow = Wm2[(size_t)m * 64 + lane];
                #pragma unroll
                for (int i = 0; i < WIN; ++i) {
                    float a = mrow[i][m];
                    acc[i].x += a * wrow.x;
                    acc[i].y += a * wrow.y;
                }
            }
            #pragma unroll
            for (int i = 0; i < WIN; ++i) pacc2[i][wave][lane] = acc[i];
        }
        __syncthreads();

        if (wave < wlen) {
            int i = wave;
            float2 s2 = {0.f, 0.f};
            #pragma unroll
            for (int w = 0; w < 8; ++w) {
                s2.x += pacc2[i][w][lane].x;
                s2.y += pacc2[i][w][lane].y;
            }
            const float2* Wl2 = (const float2*)Wloc;
            float p0 = 0.f, p1 = 0.f;
            #pragma unroll
            for (int f = 0; f < F; ++f) {
                float fv = fsh[i][f];
                float2 wv = Wl2[f * 64 + lane];
                p0 += fv * wv.x; p1 += fv * wv.y;
            }
            int c0 = 2 * lane, c1 = c0 + 1;
            float x = sv[c0] * tanhf(s2.x + pqs[c0] + p0)
                    + sv[c1] * tanhf(s2.y + pqs[c1] + p1);
            for (int o = 32; o > 0; o >>= 1) x += __shfl_xor(x, o);
            if (lane == 0) esh[i] = x;
        }
        __syncthreads();

        if (tid == 0) {
            float a[WIN];
            int best = 0;
            float mx = esh[0];
            for (int i = 1; i < wlen; ++i) if (esh[i] > mx) mx = esh[i];
            float s = 0.f;
            for (int i = 0; i < wlen; ++i) { a[i] = expf(esh[i] - mx); s += a[i]; }
            float inv = 1.f / s;
            float ab = -1.f;
            for (int i = 0; i < wlen; ++i) {
                a[i] *= inv;
                if (a[i] > ab) { ab = a[i]; best = i; }
            }
            for (int i = 0; i < WIN; ++i) ash[i] = (i < wlen) ? a[i] : 0.f;
            sbest = wstart + best;
        }
        __syncthreads();

        // window ctx -> attention GEMV (smem_a reused: qs dead after pq phase)
        {
            float s = 0.f;
            #pragma unroll
            for (int i = 0; i < WIN; ++i) s += ash[i] * mrow[i][tid];
            ctxs[tid] = s;
        }
        __syncthreads();
        {
            int col = tid & 127, j = tid >> 7;
            const float* wp = Wm + (size_t)(j * 128) * D + col;
            float acc2 = 0.f;
            for (int mm = 0; mm < 128; ++mm)
                acc2 += ctxs[j * 128 + mm] * wp[(size_t)mm * D];
            gpart[j * D + col] = acc2;
        }
        __syncthreads();
        if (tid < D)
            out[b * D + tid] = gpart[tid] + gpart[D + tid] + gpart[2 * D + tid] + gpart[3 * D + tid];
    }

    // ---------------- [B,T] outputs + argmax (before any spinning) ----------------
    {
        float invT = 1.f / (float)T;
        for (int t = tid; t < T; t += 512) {
            float a;
            if (wlen == 0) a = invT;
            else a = (t >= wstart && t < wstart + wlen) ? ash[t - wstart] : 0.f;
            out[OUT_ALIGN + b * T + t] = a;
            out[OUT_NEXT + b * T + t] = pa[(size_t)b * T + t] + a;
        }
        if (tid == 0) out[OUT_ARG + b] = (float)((wlen > 0) ? sbest : 0);
    }

    if (wlen > 0) return;

    if (!lowmem) {
        // ---------- degenerate: spin on flags, reduce partials, GEMV ----------
        if (tid < NCH) {
            while (__hip_atomic_load(&flag[b * NCH + tid],
                                     __ATOMIC_ACQUIRE, __HIP_MEMORY_SCOPE_AGENT) != SENT) {
                __builtin_amdgcn_s_sleep(8);
            }
        }
        __syncthreads();
        {
            float s = 0.f;
            #pragma unroll 8
            for (int c = 0; c < NCH; ++c)
                s += __hip_atomic_load(&part[((size_t)b * NCH + c) * DM + tid],
                                       __ATOMIC_RELAXED, __HIP_MEMORY_SCOPE_AGENT);
            ctxs[tid] = s;
        }
        __syncthreads();
        {
            int col = tid & 127, j = tid >> 7;
            const float* wp = Wm + (size_t)(j * 128) * D + col;
            float acc = 0.f;
            for (int mm = 0; mm < 128; ++mm)
                acc += ctxs[j * 128 + mm] * wp[(size_t)mm * D];
            gpart[j * D + col] = acc;
        }
        __syncthreads();
        if (tid < D)
            out[b * D + tid] = gpart[tid] + gpart[D + tid] + gpart[2 * D + tid] + gpart[3 * D + tid];
        // reset flags for the next (serialized) replay
        if (tid < NCH)
            __hip_atomic_store(&flag[b * NCH + tid], 0ULL,
                               __ATOMIC_RELAXED, __HIP_MEMORY_SCOPE_AGENT);
    } else {
        // ---------- lowmem fallback: in-block slow colsum + GEMV ----------
        const float* mp = mem + (size_t)b * T * DM + tid;
        float a0 = 0.f, a1 = 0.f, a2 = 0.f, a3 = 0.f;
        int t = 0;
        for (; t + 4 <= T; t += 4) {
            a0 += mp[0]; a1 += mp[DM]; a2 += mp[2 * DM]; a3 += mp[3 * DM];
            mp += 4 * (size_t)DM;
        }
        for (; t < T; ++t) { a0 += *mp; mp += DM; }
        ctxs[tid] = ((a0 + a1) + (a2 + a3)) * (1.f / (float)T);
        __syncthreads();
        {
            int col = tid & 127, j = tid >> 7;
            const float* wp = Wm + (size_t)(j * 128) * D + col;
            float acc = 0.f;
            for (int mm = 0; mm < 128; ++mm)
                acc += ctxs[j * 128 + mm] * wp[(size_t)mm * D];
            gpart[j * D + col] = acc;
        }
        __syncthreads();
        if (tid < D)
            out[b * D + tid] = gpart[tid] + gpart[D + tid] + gpart[2 * D + tid] + gpart[3 * D + tid];
    }
}

extern "C" void kernel_launch(void* const* d_in, const int* in_sizes, int n_in,
                              void* d_out, int out_size, void* d_ws, size_t ws_size,
                              hipStream_t stream) {
    const float* query = (const float*)d_in[0];
    const float* memory = (const float*)d_in[1];
    const float* prev_align = (const float*)d_in[2];
    const int* prev_max = (const int*)d_in[3];
    const int* mem_len = (const int*)d_in[4];
    const float* Wq = (const float*)d_in[5];
    const float* Wm = (const float*)d_in[6];
    const float* ck = (const float*)d_in[7];
    const float* cb = (const float*)d_in[8];
    const float* Wloc = (const float*)d_in[9];
    const float* sv = (const float*)d_in[10];
    const float* sb = (const float*)d_in[11];
    float* out = (float*)d_out;

    float* part = (float*)d_ws;
    unsigned long long* flag =
        (unsigned long long*)((char*)d_ws + (size_t)B * NCH * DM * 4);

    size_t need = (size_t)B * NCH * DM * 4 + (size_t)B * NCH * 8;
    int lowmem = (ws_size < need) ? 1 : 0;
    int cs_blocks = lowmem ? 0 : NCS;
    int grid = cs_blocks + B;

    KF<<<grid, 512, 0, stream>>>(query, memory, prev_align, prev_max, mem_len,
                                 Wq, Wm, ck, cb, Wloc, sv, sb,
                                 part, flag, out, cs_blocks, lowmem);
}

// Round 8
// 69.073 us; speedup vs baseline: 1.5391x; 1.5391x over previous
//
#include <hip/hip_runtime.h>

#define B    64
#define T    2000
#define DQ   1024
#define DM   512
#define D    128
#define F    32
#define KK   31
#define WIN  7
#define NCS  2048          // colsum blocks (dynamically assigned to degenerate batches)

// ws layout (floats): part[NCS][DM]  (4 MB)
// out layout (floats):
//   attention  [B][D]  @ 0
//   alignments [B][T]  @ 8192
//   next_state [B][T]  @ 8192 + B*T
//   max_att    [B]     @ 8192 + 2*B*T  (as float)
#define OUT_ALIGN 8192
#define OUT_NEXT  (8192 + B*T)
#define OUT_ARG   (8192 + 2*B*T)

// K1:
//  blocks [0,B)      : per-batch energy/softmax/[B,T] outputs/argmax
//                      + non-degenerate window-ctx GEMV -> attention
//                      (+lowmem: in-block slow degenerate colsum + GEMV)
//  blocks [B,B+NCS)  : degenerate colsum partials, DYNAMIC assignment:
//                      ballot over (pm>=ml) -> ndeg; block k serves deg-rank
//                      k%ndeg, chunk k/ndeg; float4 loads; part[k] always
//                      written (zeros if idle chunk) so K2 may sum blindly.
__global__ void __launch_bounds__(512)
K1(const float* __restrict__ q, const float* __restrict__ mem,
   const float* __restrict__ pa, const int* __restrict__ pm, const int* __restrict__ ml,
   const float* __restrict__ Wq, const float* __restrict__ Wm,
   const float* __restrict__ ck, const float* __restrict__ cb,
   const float* __restrict__ Wloc, const float* __restrict__ sv,
   const float* __restrict__ sb, float* __restrict__ part,
   float* __restrict__ out, int cs_blocks, int lowmem) {
    __shared__ __align__(16) float smem_a[DQ];   // qs during pq; later ctxs[512]+gpart[512]
    __shared__ float pqpart[4][D];
    __shared__ float pqs[D];
    __shared__ __align__(16) float mrow[WIN][DM];
    __shared__ float fsh[WIN][F];
    __shared__ __align__(16) float2 pacc2[WIN][8][64];  // energy scratch; colsum red4
    __shared__ float esh[WIN];
    __shared__ float ash[WIN];
    __shared__ int   sbest;

    float* qs = smem_a;
    float* ctxs = smem_a;
    float* gpart = smem_a + DM;

    int blk = blockIdx.x;
    int tid = threadIdx.x;

    if (blk >= B) {
        // ---------------- degenerate colsum partial (dynamic) ----------------
        int k = blk - B;
        int lane = tid & 63;
        unsigned long long mask = __ballot(pm[lane] >= ml[lane]);
        int ndeg = __popcll(mask);
        if (ndeg == 0) return;
        int j = k % ndeg, r = k / ndeg;
        int bsel = 0;
        {
            int cnt = 0;
            for (int i = 0; i < 64; ++i) {
                if ((mask >> i) & 1ULL) { if (cnt == j) { bsel = i; break; } ++cnt; }
            }
        }
        int nchunks = NCS / ndeg;                 // >= 32
        int rpb = (T + nchunks - 1) / nchunks;
        float4 acc = make_float4(0.f, 0.f, 0.f, 0.f);
        if (r < nchunks) {
            int t0 = r * rpb, t1 = t0 + rpb;
            if (t1 > T) t1 = T;
            int g = tid >> 7, c4 = tid & 127;     // 4 row-groups x 128 col4
            for (int t = t0 + g; t < t1; t += 4) {
                const float4 v = *((const float4*)(mem + ((size_t)bsel * T + t) * DM) + c4);
                acc.x += v.x; acc.y += v.y; acc.z += v.z; acc.w += v.w;
            }
        }
        float4* red4 = (float4*)pacc2;            // 8 KB of the 28 KB scratch
        red4[tid] = acc;
        __syncthreads();
        if (tid < 128) {
            float4 s0 = red4[tid], s1 = red4[tid + 128];
            float4 s2 = red4[tid + 256], s3 = red4[tid + 384];
            const float invT = 1.f / (float)T;
            float4 s;
            s.x = ((s0.x + s1.x) + (s2.x + s3.x)) * invT;
            s.y = ((s0.y + s1.y) + (s2.y + s3.y)) * invT;
            s.z = ((s0.z + s1.z) + (s2.z + s3.z)) * invT;
            s.w = ((s0.w + s1.w) + (s2.w + s3.w)) * invT;
            *((float4*)(part + (size_t)k * DM) + tid) = s;
        }
        return;
    }

    // ---------------- per-batch energy / softmax / outputs ----------------
    int b = blk;
    int lane = tid & 63;
    int wave = tid >> 6;
    int p = pm[b], L = ml[b];
    int wstart = p, wlen = 0;
    if (p < L) { int we = p + WIN; if (we > L) we = L; wlen = we - p; }

    if (wlen > 0) {
        if (tid < 256)
            ((float4*)qs)[tid] = ((const float4*)(q + (size_t)b * DQ))[tid];
        for (int e4 = tid; e4 < WIN * (DM / 4); e4 += 512) {
            int i = e4 >> 7, m4 = e4 & 127;
            float4 v = make_float4(0.f, 0.f, 0.f, 0.f);
            if (i < wlen)
                v = *((const float4*)(mem + ((size_t)b * T + wstart + i) * DM) + m4);
            *((float4*)mrow[i] + m4) = v;
        }
        if (tid < WIN * F) {
            int i = tid >> 5, f = tid & 31;
            if (i < wlen) {
                int t = wstart + i;
                float acc = cb[f];
                for (int k = 0; k < KK; ++k) {
                    int tt = t + k - 15;
                    float x = (tt >= 0 && tt < T) ? pa[(size_t)b * T + tt] : 0.f;
                    acc += x * ck[k * F + f];
                }
                fsh[i][f] = acc;
            } else if (i < WIN) {
                fsh[i][f] = 0.f;
            }
        }
        __syncthreads();

        // pq partials: (j=tid>>7, d=tid&127), each sums 256 of 1024 k
        {
            int d = tid & 127, j = tid >> 7;
            int k0 = j * 256;
            float acc = 0.f;
            for (int k = 0; k < 256; ++k)
                acc += qs[k0 + k] * Wq[(size_t)(k0 + k) * D + d];
            pqpart[j][d] = acc;
        }
        __syncthreads();
        if (tid < D)
            pqs[tid] = pqpart[0][tid] + pqpart[1][tid] + pqpart[2][tid] + pqpart[3][tid] + sb[tid];

        // m-split energies: wave w owns rows [w*64,(w+1)*64), all WIN positions
        {
            const float2* Wm2 = (const float2*)Wm;
            float2 acc[WIN];
            #pragma unroll
            for (int i = 0; i < WIN; ++i) { acc[i].x = 0.f; acc[i].y = 0.f; }
            int m0 = wave * 64;
            for (int mm = 0; mm < 64; ++mm) {
                int m = m0 + mm;
                float2 wrow = Wm2[(size_t)m * 64 + lane];
                #pragma unroll
                for (int i = 0; i < WIN; ++i) {
                    float a = mrow[i][m];
                    acc[i].x += a * wrow.x;
                    acc[i].y += a * wrow.y;
                }
            }
            #pragma unroll
            for (int i = 0; i < WIN; ++i) pacc2[i][wave][lane] = acc[i];
        }
        __syncthreads();

        if (wave < wlen) {
            int i = wave;
            float2 s2 = {0.f, 0.f};
            #pragma unroll
            for (int w = 0; w < 8; ++w) {
                s2.x += pacc2[i][w][lane].x;
                s2.y += pacc2[i][w][lane].y;
            }
            const float2* Wl2 = (const float2*)Wloc;
            float p0 = 0.f, p1 = 0.f;
            #pragma unroll
            for (int f = 0; f < F; ++f) {
                float fv = fsh[i][f];
                float2 wv = Wl2[f * 64 + lane];
                p0 += fv * wv.x; p1 += fv * wv.y;
            }
            int c0 = 2 * lane, c1 = c0 + 1;
            float x = sv[c0] * tanhf(s2.x + pqs[c0] + p0)
                    + sv[c1] * tanhf(s2.y + pqs[c1] + p1);
            for (int o = 32; o > 0; o >>= 1) x += __shfl_xor(x, o);
            if (lane == 0) esh[i] = x;
        }
        __syncthreads();

        if (tid == 0) {
            float a[WIN];
            int best = 0;
            float mx = esh[0];
            for (int i = 1; i < wlen; ++i) if (esh[i] > mx) mx = esh[i];
            float s = 0.f;
            for (int i = 0; i < wlen; ++i) { a[i] = expf(esh[i] - mx); s += a[i]; }
            float inv = 1.f / s;
            float ab = -1.f;
            for (int i = 0; i < wlen; ++i) {
                a[i] *= inv;
                if (a[i] > ab) { ab = a[i]; best = i; }
            }
            for (int i = 0; i < WIN; ++i) ash[i] = (i < wlen) ? a[i] : 0.f;
            sbest = wstart + best;
        }
        __syncthreads();

        // window ctx -> attention GEMV (smem_a reused: qs dead after pq phase)
        {
            float s = 0.f;
            #pragma unroll
            for (int i = 0; i < WIN; ++i) s += ash[i] * mrow[i][tid];
            ctxs[tid] = s;
        }
        __syncthreads();
        {
            int col = tid & 127, j = tid >> 7;
            const float* wp = Wm + (size_t)(j * 128) * D + col;
            float acc2 = 0.f;
            for (int mm = 0; mm < 128; ++mm)
                acc2 += ctxs[j * 128 + mm] * wp[(size_t)mm * D];
            gpart[j * D + col] = acc2;
        }
        __syncthreads();
        if (tid < D)
            out[b * D + tid] = gpart[tid] + gpart[D + tid] + gpart[2 * D + tid] + gpart[3 * D + tid];
    } else if (lowmem) {
        // in-block degenerate colsum (only if ws too small for partials)
        const float* mp = mem + (size_t)b * T * DM + tid;
        float a0 = 0.f, a1 = 0.f, a2 = 0.f, a3 = 0.f;
        int t = 0;
        for (; t + 4 <= T; t += 4) {
            a0 += mp[0]; a1 += mp[DM]; a2 += mp[2 * DM]; a3 += mp[3 * DM];
            mp += 4 * (size_t)DM;
        }
        for (; t < T; ++t) { a0 += *mp; mp += DM; }
        ctxs[tid] = ((a0 + a1) + (a2 + a3)) * (1.f / (float)T);
        __syncthreads();
        {
            int col = tid & 127, j = tid >> 7;
            const float* wp = Wm + (size_t)(j * 128) * D + col;
            float acc2 = 0.f;
            for (int mm = 0; mm < 128; ++mm)
                acc2 += ctxs[j * 128 + mm] * wp[(size_t)mm * D];
            gpart[j * D + col] = acc2;
        }
        __syncthreads();
        if (tid < D)
            out[b * D + tid] = gpart[tid] + gpart[D + tid] + gpart[2 * D + tid] + gpart[3 * D + tid];
    }

    // ---------------- [B,T] outputs + argmax (float4) ----------------
    {
        float invT = 1.f / (float)T;
        int t4 = tid * 4;
        if (t4 < T) {                              // 500 active threads, exact cover
            float4 pav = *(const float4*)(pa + (size_t)b * T + t4);
            float4 av;
            float* avp = &av.x;
            const float* pavp = &pav.x;
            float4 nv;
            float* nvp = &nv.x;
            #pragma unroll
            for (int jj = 0; jj < 4; ++jj) {
                int t = t4 + jj;
                float a;
                if (wlen == 0) a = invT;
                else a = (t >= wstart && t < wstart + wlen) ? ash[t - wstart] : 0.f;
                avp[jj] = a;
                nvp[jj] = pavp[jj] + a;
            }
            *(float4*)(out + OUT_ALIGN + (size_t)b * T + t4) = av;
            *(float4*)(out + OUT_NEXT + (size_t)b * T + t4) = nv;
        }
        if (tid == 0) out[OUT_ARG + b] = (float)((wlen > 0) ? sbest : 0);
    }
}

// ---------------- K2: degenerate reduce + attention GEMV ----------------
__global__ void __launch_bounds__(512)
K2(const int* __restrict__ pm, const int* __restrict__ ml,
   const float* __restrict__ part, const float* __restrict__ Wm,
   float* __restrict__ out) {
    int b = blockIdx.x;
    int tid = threadIdx.x;
    int lane = tid & 63;
    unsigned long long mask = __ballot(pm[lane] >= ml[lane]);   // all lanes vote first
    if (pm[b] < ml[b]) return;                  // non-degenerate handled in K1
    int ndeg = __popcll(mask);
    int j = (b == 0) ? 0 : __popcll(mask & ((1ULL << b) - 1ULL));
    __shared__ float ctxs[DM];
    __shared__ float gpart[4 * D];
    float s = 0.f;
    for (int k = j; k < NCS; k += ndeg)
        s += part[(size_t)k * DM + tid];
    ctxs[tid] = s;
    __syncthreads();
    {
        int col = tid & 127, jj = tid >> 7;
        const float* wp = Wm + (size_t)(jj * 128) * D + col;
        float acc = 0.f;
        for (int mm = 0; mm < 128; ++mm)
            acc += ctxs[jj * 128 + mm] * wp[(size_t)mm * D];
        gpart[jj * D + col] = acc;
    }
    __syncthreads();
    if (tid < D)
        out[b * D + tid] = gpart[tid] + gpart[D + tid] + gpart[2 * D + tid] + gpart[3 * D + tid];
}

extern "C" void kernel_launch(void* const* d_in, const int* in_sizes, int n_in,
                              void* d_out, int out_size, void* d_ws, size_t ws_size,
                              hipStream_t stream) {
    const float* query = (const float*)d_in[0];
    const float* memory = (const float*)d_in[1];
    const float* prev_align = (const float*)d_in[2];
    const int* prev_max = (const int*)d_in[3];
    const int* mem_len = (const int*)d_in[4];
    const float* Wq = (const float*)d_in[5];
    const float* Wm = (const float*)d_in[6];
    const float* ck = (const float*)d_in[7];
    const float* cb = (const float*)d_in[8];
    const float* Wloc = (const float*)d_in[9];
    const float* sv = (const float*)d_in[10];
    const float* sb = (const float*)d_in[11];
    float* out = (float*)d_out;

    float* part = (float*)d_ws;
    size_t need = (size_t)NCS * DM * 4;
    int lowmem = (ws_size < need) ? 1 : 0;
    int cs_blocks = lowmem ? 0 : NCS;
    int grid = B + cs_blocks;

    K1<<<grid, 512, 0, stream>>>(query, memory, prev_align, prev_max, mem_len,
                                 Wq, Wm, ck, cb, Wloc, sv, sb,
                                 part, out, cs_blocks, lowmem);
    if (!lowmem)
        K2<<<B, 512, 0, stream>>>(prev_max, mem_len, part, Wm, out);
}

// Round 9
// 30.951 us; speedup vs baseline: 3.4347x; 2.2317x over previous
//
#include <hip/hip_runtime.h>

#define B    64
#define T    2000
#define DQ   1024
#define DM   512
#define D    128
#define F    32
#define KK   31
#define WIN  7
#define NCH  32
#define CH   63            // ceil(T/NCH)
#define NCS  (B * NCH)     // 2048 colsum blocks
#define NPQ  (B * 4)       // 256 pq k-slice blocks

// ws layout (floats):
//   part : [B][NCH][DM] @ 0        (4 MB)
//   pq4  : [B][4][D]    @ NCS*DM   (128 KB)
#define PQ4_OFF (NCS * DM)

// out layout (floats):
//   attention  [B][D]  @ 0
//   alignments [B][T]  @ 8192
//   next_state [B][T]  @ 8192 + B*T
//   max_att    [B]     @ 8192 + 2*B*T  (as float)
#define OUT_ALIGN 8192
#define OUT_NEXT  (8192 + B*T)
#define OUT_ARG   (8192 + 2*B*T)

// ---------------- K1: colsum partials (R5-exact) + pq k-slices ----------------
//  blocks [0,NCS)          : degenerate colsum partial (b=blk>>5, c=blk&31)
//  blocks [NCS,NCS+NPQ)    : pq slice s=blk-NCS: b=s>>2, j=s&3:
//                            pq4[b][j][d] = sum_{k in [j*256,(j+1)*256)} q[b][k]*Wq[k][d]
__global__ void __launch_bounds__(512)
K1(const float* __restrict__ q, const float* __restrict__ mem,
   const int* __restrict__ pm, const int* __restrict__ ml,
   const float* __restrict__ Wq, float* __restrict__ part,
   float* __restrict__ pq4) {
    __shared__ float red[4][D];
    int blk = blockIdx.x;
    int tid = threadIdx.x;

    if (blk < NCS) {
        // ---- degenerate colsum partial (identical to R5) ----
        int b = blk >> 5, c = blk & 31;
        if (pm[b] < ml[b]) return;              // non-degenerate: nothing to do
        int t0 = c * CH, t1 = t0 + CH;
        if (t1 > T) t1 = T;
        const float* mp = mem + ((size_t)b * T + t0) * DM + tid;
        float a0 = 0.f, a1 = 0.f, a2 = 0.f, a3 = 0.f;
        int t = t0;
        for (; t + 4 <= t1; t += 4) {
            a0 += mp[0];
            a1 += mp[DM];
            a2 += mp[2 * DM];
            a3 += mp[3 * DM];
            mp += 4 * (size_t)DM;
        }
        for (; t < t1; ++t) { a0 += *mp; mp += DM; }
        part[((size_t)b * NCH + c) * DM + tid] = ((a0 + a1) + (a2 + a3)) * (1.f / (float)T);
        return;
    }

    // ---- pq slice ----
    int s = blk - NCS;
    int b = s >> 2, j = s & 3;
    int d = tid & 127, kk = tid >> 7;           // kk in [0,4)
    int k0 = j * 256 + kk * 64;
    const float* qp = q + (size_t)b * DQ + k0;
    const float* wp = Wq + (size_t)k0 * D + d;
    float acc = 0.f;
    #pragma unroll 4
    for (int k = 0; k < 64; ++k)
        acc += qp[k] * wp[(size_t)k * D];
    red[kk][d] = acc;
    __syncthreads();
    if (tid < D)
        pq4[((size_t)b * 4 + j) * D + tid] =
            (red[0][tid] + red[1][tid]) + (red[2][tid] + red[3][tid]);
}

// ---------------- K2: per-batch everything (64 blocks) ----------------
//  non-deg: pq4-read, window energies (m-split, val saved), softmax,
//           attention = sum_i a_i * val[i][:], [B,T] outputs, argmax
//  deg    : reduce part (fixed order) + GEMV -> attention, uniform outputs
//  lowmem : in-block pq (q staging) and in-block slow colsum
__global__ void __launch_bounds__(512)
K2(const float* __restrict__ q, const float* __restrict__ mem,
   const float* __restrict__ pa, const int* __restrict__ pm, const int* __restrict__ ml,
   const float* __restrict__ Wq, const float* __restrict__ Wm,
   const float* __restrict__ ck, const float* __restrict__ cb,
   const float* __restrict__ Wloc, const float* __restrict__ sv,
   const float* __restrict__ sb, const float* __restrict__ part,
   const float* __restrict__ pq4, float* __restrict__ out, int lowmem) {
    __shared__ __align__(16) float mrow[WIN][DM];      // deg: ctxs[512]+gpart[512] alias
    __shared__ float fsh[WIN][F];
    __shared__ float2 pacc2[WIN][8][64];
    __shared__ float vsh[WIN][D];
    __shared__ float pqs[D];
    __shared__ float esh[WIN];
    __shared__ float ash[WIN];
    __shared__ int   sbest;

    int b = blockIdx.x;
    int tid = threadIdx.x;
    int lane = tid & 63;
    int wave = tid >> 6;
    int p = pm[b], L = ml[b];
    int wstart = p, wlen = 0;
    if (p < L) { int we = p + WIN; if (we > L) we = L; wlen = we - p; }

    if (wlen > 0) {
        // stage window memory rows (zero unused)
        for (int e = tid; e < WIN * DM; e += 512) {
            int i = e >> 9, m = e & 511;
            mrow[i][m] = (i < wlen) ? mem[((size_t)b * T + wstart + i) * DM + m] : 0.f;
        }
        // conv location features
        if (tid < WIN * F) {
            int i = tid >> 5, f = tid & 31;
            if (i < wlen) {
                int t = wstart + i;
                float acc = cb[f];
                for (int k = 0; k < KK; ++k) {
                    int tt = t + k - 15;
                    float x = (tt >= 0 && tt < T) ? pa[(size_t)b * T + tt] : 0.f;
                    acc += x * ck[k * F + f];
                }
                fsh[i][f] = acc;
            } else if (i < WIN) {
                fsh[i][f] = 0.f;
            }
        }
        // pqs
        if (!lowmem) {
            if (tid < D) {
                const float* pp = pq4 + (size_t)b * 4 * D;
                pqs[tid] = (pp[tid] + pp[D + tid]) + (pp[2 * D + tid] + pp[3 * D + tid]) + sb[tid];
            }
        } else {
            // in-block pq: (j=tid>>7, d=tid&127) partial into pacc2 scratch
            int d = tid & 127, j = tid >> 7;
            int k0 = j * 256;
            const float* qp = q + (size_t)b * DQ + k0;
            float acc = 0.f;
            for (int k = 0; k < 256; ++k)
                acc += qp[k] * Wq[(size_t)(k0 + k) * D + d];
            ((float*)pacc2)[j * D + d] = acc;
            __syncthreads();
            if (tid < D) {
                const float* pp = (const float*)pacc2;
                pqs[tid] = (pp[tid] + pp[D + tid]) + (pp[2 * D + tid] + pp[3 * D + tid]) + sb[tid];
            }
        }
        __syncthreads();

        // m-split energies: wave w owns rows [w*64,(w+1)*64), all WIN positions
        {
            const float2* Wm2 = (const float2*)Wm;
            float2 acc[WIN];
            #pragma unroll
            for (int i = 0; i < WIN; ++i) { acc[i].x = 0.f; acc[i].y = 0.f; }
            int m0 = wave * 64;
            for (int mm = 0; mm < 64; ++mm) {
                int m = m0 + mm;
                float2 wrow = Wm2[(size_t)m * 64 + lane];
                #pragma unroll
                for (int i = 0; i < WIN; ++i) {
                    float a = mrow[i][m];
                    acc[i].x += a * wrow.x;
                    acc[i].y += a * wrow.y;
                }
            }
            #pragma unroll
            for (int i = 0; i < WIN; ++i) pacc2[i][wave][lane] = acc[i];
        }
        __syncthreads();

        if (wave < wlen) {
            int i = wave;
            float2 s2 = {0.f, 0.f};
            #pragma unroll
            for (int w = 0; w < 8; ++w) {
                s2.x += pacc2[i][w][lane].x;
                s2.y += pacc2[i][w][lane].y;
            }
            ((float2*)vsh[i])[lane] = s2;           // save raw val[i][:]
            const float2* Wl2 = (const float2*)Wloc;
            float p0 = 0.f, p1 = 0.f;
            #pragma unroll
            for (int f = 0; f < F; ++f) {
                float fv = fsh[i][f];
                float2 wv = Wl2[f * 64 + lane];
                p0 += fv * wv.x; p1 += fv * wv.y;
            }
            int c0 = 2 * lane, c1 = c0 + 1;
            float x = sv[c0] * tanhf(s2.x + pqs[c0] + p0)
                    + sv[c1] * tanhf(s2.y + pqs[c1] + p1);
            for (int o = 32; o > 0; o >>= 1) x += __shfl_xor(x, o);
            if (lane == 0) esh[i] = x;
        }
        __syncthreads();

        if (tid == 0) {
            float a[WIN];
            int best = 0;
            float mx = esh[0];
            for (int i = 1; i < wlen; ++i) if (esh[i] > mx) mx = esh[i];
            float s = 0.f;
            for (int i = 0; i < wlen; ++i) { a[i] = expf(esh[i] - mx); s += a[i]; }
            float inv = 1.f / s;
            float ab = -1.f;
            for (int i = 0; i < wlen; ++i) {
                a[i] *= inv;
                if (a[i] > ab) { ab = a[i]; best = i; }
            }
            for (int i = 0; i < WIN; ++i) ash[i] = (i < wlen) ? a[i] : 0.f;
            sbest = wstart + best;
        }
        __syncthreads();

        // attention = sum_i a_i * val[i][:]   (no second Wm pass)
        if (tid < D) {
            float a = 0.f;
            for (int i = 0; i < wlen; ++i) a += ash[i] * vsh[i][tid];
            out[b * D + tid] = a;
        }
    } else {
        // ---------------- degenerate ----------------
        float* ctxs = (float*)mrow;              // 4 KB alias (mrow unused)
        float* gpart = ((float*)mrow) + DM;
        if (!lowmem) {
            float s = 0.f;
            #pragma unroll 8
            for (int cc = 0; cc < NCH; ++cc)
                s += part[((size_t)b * NCH + cc) * DM + tid];
            ctxs[tid] = s;
        } else {
            const float* mp = mem + (size_t)b * T * DM + tid;
            float a0 = 0.f, a1 = 0.f, a2 = 0.f, a3 = 0.f;
            int t = 0;
            for (; t + 4 <= T; t += 4) {
                a0 += mp[0]; a1 += mp[DM]; a2 += mp[2 * DM]; a3 += mp[3 * DM];
                mp += 4 * (size_t)DM;
            }
            for (; t < T; ++t) { a0 += *mp; mp += DM; }
            ctxs[tid] = ((a0 + a1) + (a2 + a3)) * (1.f / (float)T);
        }
        __syncthreads();
        {
            int col = tid & 127, j = tid >> 7;
            const float* wp = Wm + (size_t)(j * 128) * D + col;
            float acc = 0.f;
            for (int mm = 0; mm < 128; ++mm)
                acc += ctxs[j * 128 + mm] * wp[(size_t)mm * D];
            gpart[j * D + col] = acc;
        }
        __syncthreads();
        if (tid < D)
            out[b * D + tid] = gpart[tid] + gpart[D + tid] + gpart[2 * D + tid] + gpart[3 * D + tid];
    }

    // ---------------- [B,T] outputs + argmax ----------------
    {
        float invT = 1.f / (float)T;
        for (int t = tid; t < T; t += 512) {
            float a;
            if (wlen == 0) a = invT;
            else a = (t >= wstart && t < wstart + wlen) ? ash[t - wstart] : 0.f;
            out[OUT_ALIGN + b * T + t] = a;
            out[OUT_NEXT + b * T + t] = pa[(size_t)b * T + t] + a;
        }
        if (tid == 0) out[OUT_ARG + b] = (float)((wlen > 0) ? sbest : 0);
    }
}

extern "C" void kernel_launch(void* const* d_in, const int* in_sizes, int n_in,
                              void* d_out, int out_size, void* d_ws, size_t ws_size,
                              hipStream_t stream) {
    const float* query = (const float*)d_in[0];
    const float* memory = (const float*)d_in[1];
    const float* prev_align = (const float*)d_in[2];
    const int* prev_max = (const int*)d_in[3];
    const int* mem_len = (const int*)d_in[4];
    const float* Wq = (const float*)d_in[5];
    const float* Wm = (const float*)d_in[6];
    const float* ck = (const float*)d_in[7];
    const float* cb = (const float*)d_in[8];
    const float* Wloc = (const float*)d_in[9];
    const float* sv = (const float*)d_in[10];
    const float* sb = (const float*)d_in[11];
    float* out = (float*)d_out;

    float* part = (float*)d_ws;
    float* pq4 = (float*)d_ws + PQ4_OFF;

    size_t need = (size_t)(NCS * DM + NPQ * D) * 4;
    int lowmem = (ws_size < need) ? 1 : 0;

    if (!lowmem)
        K1<<<NCS + NPQ, 512, 0, stream>>>(query, memory, prev_max, mem_len,
                                          Wq, part, pq4);
    K2<<<B, 512, 0, stream>>>(query, memory, prev_align, prev_max, mem_len,
                              Wq, Wm, ck, cb, Wloc, sv, sb,
                              part, pq4, out, lowmem);
}

// Round 10
// 27.417 us; speedup vs baseline: 3.8775x; 1.1289x over previous
//
#include <hip/hip_runtime.h>

#define B    64
#define T    2000
#define DQ   1024
#define DM   512
#define D    128
#define F    32
#define KK   31
#define WIN  7
#define NCH  32
#define CH   63            // ceil(T/NCH)
#define NCS  (B * NCH)     // 2048 colsum blocks
#define NPQ  (B * 4)       // 256 pq k-slice blocks

// ws layout (floats):
//   part  : [B][NCH][DM]      @ 0                  (1048576 floats)
//   pq4   : [B][4][D]         @ NCS*DM             (32768 floats)
//   vpart : [B][8][WIN][64]x2 @ NCS*DM + NPQ*D     (458752 floats)
#define PQ4_OFF (NCS * DM)
#define VP_OFF  (NCS * DM + NPQ * D)

// out layout (floats):
//   attention  [B][D]  @ 0
//   alignments [B][T]  @ 8192
//   next_state [B][T]  @ 8192 + B*T
//   max_att    [B]     @ 8192 + 2*B*T  (as float)
#define OUT_ALIGN 8192
#define OUT_NEXT  (8192 + B*T)
#define OUT_ARG   (8192 + 2*B*T)

// ---------------- K1: colsum + val + pq (all parallel, no sync) ----------------
//  blocks [0,NCS)            : degenerate colsum partial (b=blk>>5, c=blk&31)
//  blocks [NCS,NCS+B)        : val block for batch b: wave w computes
//                              vpart[b][w][i][lane] = sum_{m in w-slice} mrow[i][m]*Wm2[m][lane]
//  blocks [NCS+B,NCS+B+NPQ)  : pq slice (b, j): pq4[b][j][:] over k in [j*256,(j+1)*256)
__global__ void __launch_bounds__(512)
K1(const float* __restrict__ q, const float* __restrict__ mem,
   const int* __restrict__ pm, const int* __restrict__ ml,
   const float* __restrict__ Wq, const float* __restrict__ Wm,
   float* __restrict__ part, float* __restrict__ pq4, float* __restrict__ vpart) {
    __shared__ float red[4][D];
    __shared__ __align__(16) float mrow[WIN][DM];
    int blk = blockIdx.x;
    int tid = threadIdx.x;

    if (blk < NCS) {
        // ---- degenerate colsum partial (R9-exact) ----
        int b = blk >> 5, c = blk & 31;
        if (pm[b] < ml[b]) return;              // non-degenerate: nothing to do
        int t0 = c * CH, t1 = t0 + CH;
        if (t1 > T) t1 = T;
        const float* mp = mem + ((size_t)b * T + t0) * DM + tid;
        float a0 = 0.f, a1 = 0.f, a2 = 0.f, a3 = 0.f;
        int t = t0;
        for (; t + 4 <= t1; t += 4) {
            a0 += mp[0];
            a1 += mp[DM];
            a2 += mp[2 * DM];
            a3 += mp[3 * DM];
            mp += 4 * (size_t)DM;
        }
        for (; t < t1; ++t) { a0 += *mp; mp += DM; }
        part[((size_t)b * NCH + c) * DM + tid] = ((a0 + a1) + (a2 + a3)) * (1.f / (float)T);
        return;
    }

    if (blk < NCS + B) {
        // ---- val block: m-split energies partials for batch b ----
        int b = blk - NCS;
        int p = pm[b], L = ml[b];
        int wstart = p, wlen = 0;
        if (p < L) { int we = p + WIN; if (we > L) we = L; wlen = we - p; }
        if (wlen == 0) return;
        for (int e = tid; e < WIN * DM; e += 512) {
            int i = e >> 9, m = e & 511;
            mrow[i][m] = (i < wlen) ? mem[((size_t)b * T + wstart + i) * DM + m] : 0.f;
        }
        __syncthreads();
        int lane = tid & 63, wave = tid >> 6;
        const float2* Wm2 = (const float2*)Wm;
        float2 acc[WIN];
        #pragma unroll
        for (int i = 0; i < WIN; ++i) { acc[i].x = 0.f; acc[i].y = 0.f; }
        int m0 = wave * 64;
        for (int mm = 0; mm < 64; ++mm) {
            int m = m0 + mm;
            float2 wrow = Wm2[(size_t)m * 64 + lane];
            #pragma unroll
            for (int i = 0; i < WIN; ++i) {
                float a = mrow[i][m];
                acc[i].x += a * wrow.x;
                acc[i].y += a * wrow.y;
            }
        }
        float2* vp = (float2*)vpart + ((size_t)b * 8 + wave) * (WIN * 64);
        #pragma unroll
        for (int i = 0; i < WIN; ++i) vp[i * 64 + lane] = acc[i];
        return;
    }

    // ---- pq slice (R9-exact) ----
    int s = blk - NCS - B;
    int b = s >> 2, j = s & 3;
    int d = tid & 127, kk = tid >> 7;           // kk in [0,4)
    int k0 = j * 256 + kk * 64;
    const float* qp = q + (size_t)b * DQ + k0;
    const float* wp = Wq + (size_t)k0 * D + d;
    float acc = 0.f;
    #pragma unroll 4
    for (int k = 0; k < 64; ++k)
        acc += qp[k] * wp[(size_t)k * D];
    red[kk][d] = acc;
    __syncthreads();
    if (tid < D)
        pq4[((size_t)b * 4 + j) * D + tid] =
            (red[0][tid] + red[1][tid]) + (red[2][tid] + red[3][tid]);
}

// ---------------- K2: per-batch finish (64 light blocks) ----------------
__global__ void __launch_bounds__(512)
K2(const float* __restrict__ pa, const int* __restrict__ pm, const int* __restrict__ ml,
   const float* __restrict__ Wm, const float* __restrict__ ck, const float* __restrict__ cb,
   const float* __restrict__ Wloc, const float* __restrict__ sv, const float* __restrict__ sb,
   const float* __restrict__ part, const float* __restrict__ pq4,
   const float* __restrict__ vpart, float* __restrict__ out) {
    __shared__ float fsh[WIN][F];
    __shared__ float vsh[WIN][D];
    __shared__ float pqs[D];
    __shared__ float esh[WIN];
    __shared__ float ash[WIN];
    __shared__ int   sbest;
    __shared__ __align__(16) float cg[DM + 4 * D];   // deg: ctxs[512] + gpart[512]

    int b = blockIdx.x;
    int tid = threadIdx.x;
    int lane = tid & 63;
    int wave = tid >> 6;
    int p = pm[b], L = ml[b];
    int wstart = p, wlen = 0;
    if (p < L) { int we = p + WIN; if (we > L) we = L; wlen = we - p; }

    if (wlen > 0) {
        // conv location features
        if (tid < WIN * F) {
            int i = tid >> 5, f = tid & 31;
            if (i < wlen) {
                int t = wstart + i;
                float acc = cb[f];
                for (int k = 0; k < KK; ++k) {
                    int tt = t + k - 15;
                    float x = (tt >= 0 && tt < T) ? pa[(size_t)b * T + tt] : 0.f;
                    acc += x * ck[k * F + f];
                }
                fsh[i][f] = acc;
            } else if (i < WIN) {
                fsh[i][f] = 0.f;
            }
        }
        if (tid < D) {
            const float* pp = pq4 + (size_t)b * 4 * D;
            pqs[tid] = (pp[tid] + pp[D + tid]) + (pp[2 * D + tid] + pp[3 * D + tid]) + sb[tid];
        }
        __syncthreads();

        // finish energies: wave i sums the 8 w-partials (fixed order) then tanh
        if (wave < wlen) {
            int i = wave;
            const float2* vp = (const float2*)vpart + (size_t)b * 8 * (WIN * 64);
            float2 s2 = {0.f, 0.f};
            #pragma unroll
            for (int w = 0; w < 8; ++w) {
                float2 v = vp[(size_t)w * (WIN * 64) + i * 64 + lane];
                s2.x += v.x;
                s2.y += v.y;
            }
            ((float2*)vsh[i])[lane] = s2;           // save raw val[i][:]
            const float2* Wl2 = (const float2*)Wloc;
            float p0 = 0.f, p1 = 0.f;
            #pragma unroll
            for (int f = 0; f < F; ++f) {
                float fv = fsh[i][f];
                float2 wv = Wl2[f * 64 + lane];
                p0 += fv * wv.x; p1 += fv * wv.y;
            }
            int c0 = 2 * lane, c1 = c0 + 1;
            float x = sv[c0] * tanhf(s2.x + pqs[c0] + p0)
                    + sv[c1] * tanhf(s2.y + pqs[c1] + p1);
            for (int o = 32; o > 0; o >>= 1) x += __shfl_xor(x, o);
            if (lane == 0) esh[i] = x;
        }
        __syncthreads();

        if (tid == 0) {
            float a[WIN];
            int best = 0;
            float mx = esh[0];
            for (int i = 1; i < wlen; ++i) if (esh[i] > mx) mx = esh[i];
            float s = 0.f;
            for (int i = 0; i < wlen; ++i) { a[i] = expf(esh[i] - mx); s += a[i]; }
            float inv = 1.f / s;
            float ab = -1.f;
            for (int i = 0; i < wlen; ++i) {
                a[i] *= inv;
                if (a[i] > ab) { ab = a[i]; best = i; }
            }
            for (int i = 0; i < WIN; ++i) ash[i] = (i < wlen) ? a[i] : 0.f;
            sbest = wstart + best;
        }
        __syncthreads();

        // attention = sum_i a_i * val[i][:]
        if (tid < D) {
            float a = 0.f;
            for (int i = 0; i < wlen; ++i) a += ash[i] * vsh[i][tid];
            out[b * D + tid] = a;
        }
    } else {
        // ---------------- degenerate: reduce part (fixed order) + GEMV ----------
        float* ctxs = cg;
        float* gpart = cg + DM;
        float s = 0.f;
        #pragma unroll 8
        for (int cc = 0; cc < NCH; ++cc)
            s += part[((size_t)b * NCH + cc) * DM + tid];
        ctxs[tid] = s;
        __syncthreads();
        {
            int col = tid & 127, j = tid >> 7;
            const float* wp = Wm + (size_t)(j * 128) * D + col;
            float acc = 0.f;
            for (int mm = 0; mm < 128; ++mm)
                acc += ctxs[j * 128 + mm] * wp[(size_t)mm * D];
            gpart[j * D + col] = acc;
        }
        __syncthreads();
        if (tid < D)
            out[b * D + tid] = gpart[tid] + gpart[D + tid] + gpart[2 * D + tid] + gpart[3 * D + tid];
    }

    // ---------------- [B,T] outputs + argmax ----------------
    {
        float invT = 1.f / (float)T;
        for (int t = tid; t < T; t += 512) {
            float a;
            if (wlen == 0) a = invT;
            else a = (t >= wstart && t < wstart + wlen) ? ash[t - wstart] : 0.f;
            out[OUT_ALIGN + b * T + t] = a;
            out[OUT_NEXT + b * T + t] = pa[(size_t)b * T + t] + a;
        }
        if (tid == 0) out[OUT_ARG + b] = (float)((wlen > 0) ? sbest : 0);
    }
}

// ---------------- K2L: lowmem all-in-one fallback (R9 K2 with lowmem=1) ----------
__global__ void __launch_bounds__(512)
K2L(const float* __restrict__ q, const float* __restrict__ mem,
    const float* __restrict__ pa, const int* __restrict__ pm, const int* __restrict__ ml,
    const float* __restrict__ Wq, const float* __restrict__ Wm,
    const float* __restrict__ ck, const float* __restrict__ cb,
    const float* __restrict__ Wloc, const float* __restrict__ sv,
    const float* __restrict__ sb, float* __restrict__ out) {
    __shared__ __align__(16) float mrow[WIN][DM];
    __shared__ float fsh[WIN][F];
    __shared__ float2 pacc2[WIN][8][64];
    __shared__ float vsh[WIN][D];
    __shared__ float pqs[D];
    __shared__ float esh[WIN];
    __shared__ float ash[WIN];
    __shared__ int   sbest;

    int b = blockIdx.x;
    int tid = threadIdx.x;
    int lane = tid & 63;
    int wave = tid >> 6;
    int p = pm[b], L = ml[b];
    int wstart = p, wlen = 0;
    if (p < L) { int we = p + WIN; if (we > L) we = L; wlen = we - p; }

    if (wlen > 0) {
        for (int e = tid; e < WIN * DM; e += 512) {
            int i = e >> 9, m = e & 511;
            mrow[i][m] = (i < wlen) ? mem[((size_t)b * T + wstart + i) * DM + m] : 0.f;
        }
        if (tid < WIN * F) {
            int i = tid >> 5, f = tid & 31;
            if (i < wlen) {
                int t = wstart + i;
                float acc = cb[f];
                for (int k = 0; k < KK; ++k) {
                    int tt = t + k - 15;
                    float x = (tt >= 0 && tt < T) ? pa[(size_t)b * T + tt] : 0.f;
                    acc += x * ck[k * F + f];
                }
                fsh[i][f] = acc;
            } else if (i < WIN) {
                fsh[i][f] = 0.f;
            }
        }
        {
            int d = tid & 127, j = tid >> 7;
            int k0 = j * 256;
            const float* qp = q + (size_t)b * DQ + k0;
            float acc = 0.f;
            for (int k = 0; k < 256; ++k)
                acc += qp[k] * Wq[(size_t)(k0 + k) * D + d];
            ((float*)pacc2)[j * D + d] = acc;
            __syncthreads();
            if (tid < D) {
                const float* pp = (const float*)pacc2;
                pqs[tid] = (pp[tid] + pp[D + tid]) + (pp[2 * D + tid] + pp[3 * D + tid]) + sb[tid];
            }
        }
        __syncthreads();
        {
            const float2* Wm2 = (const float2*)Wm;
            float2 acc[WIN];
            #pragma unroll
            for (int i = 0; i < WIN; ++i) { acc[i].x = 0.f; acc[i].y = 0.f; }
            int m0 = wave * 64;
            for (int mm = 0; mm < 64; ++mm) {
                int m = m0 + mm;
                float2 wrow = Wm2[(size_t)m * 64 + lane];
                #pragma unroll
                for (int i = 0; i < WIN; ++i) {
                    float a = mrow[i][m];
                    acc[i].x += a * wrow.x;
                    acc[i].y += a * wrow.y;
                }
            }
            #pragma unroll
            for (int i = 0; i < WIN; ++i) pacc2[i][wave][lane] = acc[i];
        }
        __syncthreads();
        if (wave < wlen) {
            int i = wave;
            float2 s2 = {0.f, 0.f};
            #pragma unroll
            for (int w = 0; w < 8; ++w) {
                s2.x += pacc2[i][w][lane].x;
                s2.y += pacc2[i][w][lane].y;
            }
            ((float2*)vsh[i])[lane] = s2;
            const float2* Wl2 = (const float2*)Wloc;
            float p0 = 0.f, p1 = 0.f;
            #pragma unroll
            for (int f = 0; f < F; ++f) {
                float fv = fsh[i][f];
                float2 wv = Wl2[f * 64 + lane];
                p0 += fv * wv.x; p1 += fv * wv.y;
            }
            int c0 = 2 * lane, c1 = c0 + 1;
            float x = sv[c0] * tanhf(s2.x + pqs[c0] + p0)
                    + sv[c1] * tanhf(s2.y + pqs[c1] + p1);
            for (int o = 32; o > 0; o >>= 1) x += __shfl_xor(x, o);
            if (lane == 0) esh[i] = x;
        }
        __syncthreads();
        if (tid == 0) {
            float a[WIN];
            int best = 0;
            float mx = esh[0];
            for (int i = 1; i < wlen; ++i) if (esh[i] > mx) mx = esh[i];
            float s = 0.f;
            for (int i = 0; i < wlen; ++i) { a[i] = expf(esh[i] - mx); s += a[i]; }
            float inv = 1.f / s;
            float ab = -1.f;
            for (int i = 0; i < wlen; ++i) {
                a[i] *= inv;
                if (a[i] > ab) { ab = a[i]; best = i; }
            }
            for (int i = 0; i < WIN; ++i) ash[i] = (i < wlen) ? a[i] : 0.f;
            sbest = wstart + best;
        }
        __syncthreads();
        if (tid < D) {
            float a = 0.f;
            for (int i = 0; i < wlen; ++i) a += ash[i] * vsh[i][tid];
            out[b * D + tid] = a;
        }
    } else {
        float* ctxs = (float*)mrow;
        float* gpart = ((float*)mrow) + DM;
        const float* mp = mem + (size_t)b * T * DM + tid;
        float a0 = 0.f, a1 = 0.f, a2 = 0.f, a3 = 0.f;
        int t = 0;
        for (; t + 4 <= T; t += 4) {
            a0 += mp[0]; a1 += mp[DM]; a2 += mp[2 * DM]; a3 += mp[3 * DM];
            mp += 4 * (size_t)DM;
        }
        for (; t < T; ++t) { a0 += *mp; mp += DM; }
        ctxs[tid] = ((a0 + a1) + (a2 + a3)) * (1.f / (float)T);
        __syncthreads();
        {
            int col = tid & 127, j = tid >> 7;
            const float* wp = Wm + (size_t)(j * 128) * D + col;
            float acc = 0.f;
            for (int mm = 0; mm < 128; ++mm)
                acc += ctxs[j * 128 + mm] * wp[(size_t)mm * D];
            gpart[j * D + col] = acc;
        }
        __syncthreads();
        if (tid < D)
            out[b * D + tid] = gpart[tid] + gpart[D + tid] + gpart[2 * D + tid] + gpart[3 * D + tid];
    }

    {
        float invT = 1.f / (float)T;
        for (int t = tid; t < T; t += 512) {
            float a;
            if (wlen == 0) a = invT;
            else a = (t >= wstart && t < wstart + wlen) ? ash[t - wstart] : 0.f;
            out[OUT_ALIGN + b * T + t] = a;
            out[OUT_NEXT + b * T + t] = pa[(size_t)b * T + t] + a;
        }
        if (tid == 0) out[OUT_ARG + b] = (float)((wlen > 0) ? sbest : 0);
    }
}

extern "C" void kernel_launch(void* const* d_in, const int* in_sizes, int n_in,
                              void* d_out, int out_size, void* d_ws, size_t ws_size,
                              hipStream_t stream) {
    const float* query = (const float*)d_in[0];
    const float* memory = (const float*)d_in[1];
    const float* prev_align = (const float*)d_in[2];
    const int* prev_max = (const int*)d_in[3];
    const int* mem_len = (const int*)d_in[4];
    const float* Wq = (const float*)d_in[5];
    const float* Wm = (const float*)d_in[6];
    const float* ck = (const float*)d_in[7];
    const float* cb = (const float*)d_in[8];
    const float* Wloc = (const float*)d_in[9];
    const float* sv = (const float*)d_in[10];
    const float* sb = (const float*)d_in[11];
    float* out = (float*)d_out;

    float* part = (float*)d_ws;
    float* pq4 = (float*)d_ws + PQ4_OFF;
    float* vpart = (float*)d_ws + VP_OFF;

    size_t need = (size_t)(VP_OFF + B * 8 * WIN * 64 * 2) * 4;
    int lowmem = (ws_size < need) ? 1 : 0;

    if (!lowmem) {
        K1<<<NCS + B + NPQ, 512, 0, stream>>>(query, memory, prev_max, mem_len,
                                              Wq, Wm, part, pq4, vpart);
        K2<<<B, 512, 0, stream>>>(prev_align, prev_max, mem_len, Wm, ck, cb,
                                  Wloc, sv, sb, part, pq4, vpart, out);
    } else {
        K2L<<<B, 512, 0, stream>>>(query, memory, prev_align, prev_max, mem_len,
                                   Wq, Wm, ck, cb, Wloc, sv, sb, out);
    }
}